// Round 8
// baseline (59.521 us; speedup 1.0000x reference)
//
#include <hip/hip_runtime.h>
#include <hip/hip_bf16.h>

#define D_DIM 256
#define K_CODES 1024
#define N_ROWS (32 * 1024)
#define BLOCK_ROWS 64                 // rows per block; each wave does ALL 64
#define NBLK (N_ROWS / BLOCK_ROWS)    // 512 main blocks
#define STEPS 32                      // 16-code tiles per wave (512 codes)
#define TILE_SH 4128                  // shorts per tile: 8KB frags + 64B enorm

typedef __attribute__((ext_vector_type(8))) short bf16x8;
typedef __attribute__((ext_vector_type(4))) float f32x4;

#define MFMA16 __builtin_amdgcn_mfma_f32_16x16x32_bf16

static __device__ __forceinline__ short f2bf(float f) {
    __hip_bfloat16 h = __float2bfloat16(f);   // RNE
    return *reinterpret_cast<short*>(&h);
}

static __device__ __forceinline__ bf16x8 pack8(float4 a, float4 b) {
    bf16x8 r;
    r[0] = f2bf(a.x); r[1] = f2bf(a.y); r[2] = f2bf(a.z); r[3] = f2bf(a.w);
    r[4] = f2bf(b.x); r[5] = f2bf(b.y); r[6] = f2bf(b.z); r[7] = f2bf(b.w);
    return r;
}

static __device__ __forceinline__ void gload_lds16(const void* g, void* s) {
    __builtin_amdgcn_global_load_lds(
        (const __attribute__((address_space(1))) void*)g,
        (__attribute__((address_space(3))) void*)s, 16, 0, 0);
}
static __device__ __forceinline__ void gload_lds4(const void* g, void* s) {
    __builtin_amdgcn_global_load_lds(
        (const __attribute__((address_space(1))) void*)g,
        (__attribute__((address_space(3))) void*)s, 4, 0, 0);
}

// ---------------------------------------------------------------- prep
// Fused: (a) enorm[k] = ||E[k]||^2  (one wave per code row)
//        (b) Eb = bf16(-2*E) in MFMA B-fragment order (blocks 0..127)
// frag g = t*512 + kk*64 + l holds E[code = t*16 + (l&15)][d = kk*32 + (l>>4)*8 ..+8]
__global__ __launch_bounds__(256) void vq_prep(const float* __restrict__ E,
                                               float* __restrict__ enorm,
                                               short* __restrict__ Eb) {
    int wave = threadIdx.x >> 6;
    int lane = threadIdx.x & 63;
    int k = blockIdx.x * 4 + wave;               // [0,1024)
    const float4 v = *reinterpret_cast<const float4*>(E + k * D_DIM + lane * 4);
    float s = v.x * v.x + v.y * v.y + v.z * v.z + v.w * v.w;
    #pragma unroll
    for (int off = 32; off; off >>= 1) s += __shfl_xor(s, off, 64);
    if (lane == 0) enorm[k] = s;

    if (blockIdx.x < 128) {
        int g = blockIdx.x * 256 + threadIdx.x;  // [0, 32768)
        int t = g >> 9;
        int kk = (g >> 6) & 7;
        int l = g & 63;
        int code = t * 16 + (l & 15);
        int d = kk * 32 + ((l >> 4) << 3);
        const float* src = E + (size_t)code * D_DIM + d;
        float4 v0 = *reinterpret_cast<const float4*>(src);
        float4 v1 = *reinterpret_cast<const float4*>(src + 4);
        v0.x *= -2.f; v0.y *= -2.f; v0.z *= -2.f; v0.w *= -2.f;
        v1.x *= -2.f; v1.y *= -2.f; v1.z *= -2.f; v1.w *= -2.f;
        *reinterpret_cast<bf16x8*>(Eb + (size_t)g * 8) = pack8(v0, v1);
    }
}

// ---------------------------------------------------------------- main
// Block = 64 rows, 2 waves. Wave kg handles ALL 64 rows (4 MFMA rowsets,
// A in registers) x codes [kg*512, kg*512+512) in 32 tiles of 16.
// Each wave triple-buffers its OWN B-tiles in LDS via global_load_lds,
// 2 tiles in flight, ordered purely by counted s_waitcnt vmcnt(9):
// NO barriers in the main loop (wave-private staging).
__global__ __launch_bounds__(128, 1) void vq_main(const float* __restrict__ X,
                                                  const float* __restrict__ E,
                                                  const float* __restrict__ enorm,
                                                  const short* __restrict__ Eb,
                                                  float* __restrict__ outq,
                                                  float* __restrict__ loss_partial) {
    __shared__ short lds[2][3][TILE_SH];   // ~49.5 KB, wave-private per kg
    __shared__ float mv[2][BLOCK_ROWS];
    __shared__ int   mi[2][BLOCK_ROWS];
    __shared__ int   fidx[BLOCK_ROWS];
    __shared__ float wsum[2];

    const int tid  = threadIdx.x;
    const int kg   = tid >> 6;    // wave id = K-group
    const int l    = tid & 63;
    const int lr   = l & 15;      // A row-in-16 / B,C code col
    const int lk   = l >> 4;
    const int brow0 = blockIdx.x * BLOCK_ROWS;

    // 9 loads per stage: 8 fragment chunks (16B/lane) + 16 enorm floats
#define STAGE(TT, BUF)                                                        \
    do {                                                                      \
        const int tg_ = kg * STEPS + (TT);                                    \
        _Pragma("unroll")                                                     \
        for (int kk = 0; kk < 8; ++kk)                                        \
            gload_lds16(Eb + ((size_t)tg_ * 512 + kk * 64 + l) * 8,           \
                        &lds[kg][BUF][kk * 512]);                             \
        if (l < 16) gload_lds4(enorm + tg_ * 16 + l, &lds[kg][BUF][4096]);    \
    } while (0)

    STAGE(0, 0);   // 9 loads (oldest)
    STAGE(1, 1);   // 9 loads

    // ---- prologue: 64 rows of X -> 4 bf16 A-fragment sets (this wave)
    bf16x8 a[4][8];
    #pragma unroll
    for (int s = 0; s < 4; ++s) {
        const float* xp = X + (size_t)(brow0 + s * 16 + lr) * D_DIM + lk * 8;
        #pragma unroll
        for (int kk = 0; kk < 8; ++kk) {
            float4 p = *reinterpret_cast<const float4*>(xp + kk * 32);
            float4 q = *reinterpret_cast<const float4*>(xp + kk * 32 + 4);
            a[s][kk] = pack8(p, q);
        }
    }

    float minv[4][4];
    int   mini[4][4];
    #pragma unroll
    for (int s = 0; s < 4; ++s)
        #pragma unroll
        for (int i = 0; i < 4; ++i) { minv[s][i] = INFINITY; mini[s][i] = 0; }

    // Step body: wait for tile TT staged (9 = the two newer stages in
    // flight), read fragments, issue stage TT+2, 32 MFMA, argmin update.
#define STEP(TT, WAITN, DO_STAGE)                                             \
    do {                                                                      \
        const int buf_ = (TT) % 3;                                            \
        asm volatile("s_waitcnt vmcnt(" #WAITN ")" ::: "memory");             \
        __builtin_amdgcn_sched_barrier(0);                                    \
        bf16x8 b[8];                                                          \
        _Pragma("unroll")                                                     \
        for (int kk = 0; kk < 8; ++kk)                                        \
            b[kk] = *reinterpret_cast<const bf16x8*>(                         \
                &lds[kg][buf_][kk * 512 + l * 8]);                            \
        const float en = *reinterpret_cast<const float*>(                     \
            &lds[kg][buf_][4096 + lr * 2]);                                   \
        if (DO_STAGE) STAGE((TT) + 2, ((TT) + 2) % 3);                        \
        f32x4 acc0 = {0,0,0,0}, acc1 = {0,0,0,0};                             \
        f32x4 acc2 = {0,0,0,0}, acc3 = {0,0,0,0};                             \
        _Pragma("unroll")                                                     \
        for (int kk = 0; kk < 8; ++kk) {                                      \
            acc0 = MFMA16(a[0][kk], b[kk], acc0, 0, 0, 0);                    \
            acc1 = MFMA16(a[1][kk], b[kk], acc1, 0, 0, 0);                    \
            acc2 = MFMA16(a[2][kk], b[kk], acc2, 0, 0, 0);                    \
            acc3 = MFMA16(a[3][kk], b[kk], acc3, 0, 0, 0);                    \
        }                                                                     \
        const int idx_ = (kg * STEPS + (TT)) * 16 + lr;                       \
        _Pragma("unroll")                                                     \
        for (int i = 0; i < 4; ++i) {                                         \
            float s0 = acc0[i] + en, s1 = acc1[i] + en;                       \
            float s2 = acc2[i] + en, s3 = acc3[i] + en;                       \
            if (s0 < minv[0][i]) { minv[0][i] = s0; mini[0][i] = idx_; }      \
            if (s1 < minv[1][i]) { minv[1][i] = s1; mini[1][i] = idx_; }      \
            if (s2 < minv[2][i]) { minv[2][i] = s2; mini[2][i] = idx_; }      \
            if (s3 < minv[3][i]) { minv[3][i] = s3; mini[3][i] = idx_; }      \
        }                                                                     \
    } while (0)

    for (int tt = 0; tt < STEPS - 2; ++tt) STEP(tt, 9, true);
    STEP(STEPS - 2, 9, false);
    STEP(STEPS - 1, 0, false);
#undef STEP
#undef STAGE

    // ---- reduce over the 16 code-lanes (first-min tie-break)
    #pragma unroll
    for (int off = 8; off >= 1; off >>= 1) {
        #pragma unroll
        for (int s = 0; s < 4; ++s)
            #pragma unroll
            for (int i = 0; i < 4; ++i) {
                float ov = __shfl_xor(minv[s][i], off, 64);
                int   oi = __shfl_xor(mini[s][i], off, 64);
                if (ov < minv[s][i] || (ov == minv[s][i] && oi < mini[s][i])) {
                    minv[s][i] = ov; mini[s][i] = oi;
                }
            }
    }

    // ---- publish per-wave results, merge the 2 K-groups
    if (lr == 0) {
        #pragma unroll
        for (int s = 0; s < 4; ++s)
            #pragma unroll
            for (int i = 0; i < 4; ++i) {
                mv[kg][s * 16 + lk * 4 + i] = minv[s][i];
                mi[kg][s * 16 + lk * 4 + i] = mini[s][i];
            }
    }
    __syncthreads();
    if (tid < BLOCK_ROWS) {
        float bv = mv[0][tid]; int bi = mi[0][tid];
        float v  = mv[1][tid]; int ii = mi[1][tid];
        if (v < bv || (v == bv && ii < bi)) { bv = v; bi = ii; }
        fidx[tid] = bi;
    }
    __syncthreads();

    // ---- fused gather-writeback + loss (8 threads/row, 16 rows/pass)
    float lsum = 0.0f;
    #pragma unroll
    for (int p = 0; p < 4; ++p) {
        const int r   = p * 16 + (tid >> 3);
        const int c8  = tid & 7;
        const int row = brow0 + r;
        const int idx = fidx[r];
        const float* eq  = E + (size_t)idx * D_DIM;
        const float* xr  = X + (size_t)row * D_DIM;
        float*       orw = outq + (size_t)row * D_DIM;
        #pragma unroll
        for (int j = 0; j < 8; ++j) {
            int d = c8 * 4 + j * 32;
            float4 q = *reinterpret_cast<const float4*>(eq + d);
            float4 x = *reinterpret_cast<const float4*>(xr + d);
            f32x4 qv = {q.x, q.y, q.z, q.w};
            __builtin_nontemporal_store(qv, reinterpret_cast<f32x4*>(orw + d));
            float dx = q.x - x.x, dy = q.y - x.y, dz = q.z - x.z, dw = q.w - x.w;
            lsum += dx * dx + dy * dy + dz * dz + dw * dw;
        }
    }
    #pragma unroll
    for (int off = 32; off; off >>= 1) lsum += __shfl_xor(lsum, off, 64);
    if (l == 0) wsum[kg] = lsum;
    __syncthreads();
    if (tid == 0)
        loss_partial[blockIdx.x] = wsum[0] + wsum[1];
}

// ---------------------------------------------------------------- finalize
// deterministic fold of 512 block partials -> vq_loss scalar
__global__ __launch_bounds__(256) void vq_finalize(const float* __restrict__ partials,
                                                   float* __restrict__ out_loss) {
    __shared__ float s[256];
    int t = threadIdx.x;
    s[t] = partials[t] + partials[t + 256];
    __syncthreads();
    #pragma unroll
    for (int off = 128; off; off >>= 1) {
        if (t < off) s[t] += s[t + off];
        __syncthreads();
    }
    if (t == 0)
        out_loss[0] = s[0] * (1.25f / (float)((size_t)N_ROWS * D_DIM));
}

// ---------------------------------------------------------------- launch
extern "C" void kernel_launch(void* const* d_in, const int* in_sizes, int n_in,
                              void* d_out, int out_size, void* d_ws, size_t ws_size,
                              hipStream_t stream) {
    const float* X = (const float*)d_in[0];   // latents  [32768, 256] f32
    const float* E = (const float*)d_in[1];   // codebook [1024, 256]  f32
    float* out = (float*)d_out;               // 8388608 quantized + 1 loss

    float* enorm    = (float*)d_ws;                       // 1024 f32
    float* partials = enorm + K_CODES;                    // 512 f32 (1024 slot)
    short* Eb       = (short*)(partials + 1024);          // 512 KB bf16, 16B-aligned

    vq_prep    <<<256,  256, 0, stream>>>(E, enorm, Eb);
    vq_main    <<<NBLK, 128, 0, stream>>>(X, E, enorm, Eb, out, partials);
    vq_finalize<<<1,    256, 0, stream>>>(partials, out + (size_t)N_ROWS * D_DIM);
}